// Round 5
// baseline (256.951 us; speedup 1.0000x reference)
//
#include <hip/hip_runtime.h>
#include <hip/hip_bf16.h>

typedef __attribute__((ext_vector_type(4))) float v4f;
typedef __attribute__((ext_vector_type(16))) float v16f;
typedef __attribute__((ext_vector_type(8))) short v8s;
typedef __attribute__((ext_vector_type(4))) unsigned v4u;
typedef __attribute__((ext_vector_type(2))) unsigned v2u;

// full RNE fp32->bf16 (prep kernel only)
__device__ __forceinline__ short f2bf(float f) {
  union { float f; unsigned u; } v; v.f = f;
  unsigned r = v.u + 0x7FFFu + ((v.u >> 16) & 1u);
  return (short)(r >> 16);
}
// packed 2xfp32 -> bf16x2, single v_cvt_pk_bf16_f32
__device__ __forceinline__ unsigned pk2(float a, float b) {
  union { __hip_bfloat162 h; unsigned u; } c;
  c.h = __float22bfloat162_rn(make_float2(a, b));
  return c.u;
}
// bf16x2 dword -> two f32
__device__ __forceinline__ float bflo(unsigned u) {
  union { float f; unsigned u; } v; v.u = u << 16; return v.f;
}
__device__ __forceinline__ float bfhi(unsigned u) {
  union { float f; unsigned u; } v; v.u = u & 0xFFFF0000u; return v.f;
}

// prep: pack W1 [128x256] + W2 [256x256] into 32x32x16 MFMA A-fragment order
// (bf16), and convert x_user/x_movie f32 -> bf16 tables (RNE; identical to the
// old in-register conversion -> same numerics, half the gather bytes).
// 32x32x16 A-operand: lane l of fragment (nt, kt) holds
//   A'[n = nt*32 + (l&31)][k = kt*16 + (l>>5)*8 + j], j = 0..7
__global__ void prep(const float* __restrict__ W1, const float* __restrict__ W2,
                     const float* __restrict__ xu, const float* __restrict__ xm,
                     short* __restrict__ pW1, short* __restrict__ pW2,
                     short* __restrict__ xub, short* __restrict__ xmb,
                     int Nu, int Nm) {
  int tid = blockIdx.x * 256 + threadIdx.x;
  if (tid < 32768) {
    int j = tid & 7, l = (tid >> 3) & 63, frag = tid >> 9;   // frag 0..63
    int nt = frag >> 3, kt = frag & 7;
    int n = nt * 32 + (l & 31);
    int k = kt * 16 + ((l >> 5) * 8) + j;
    pW1[tid] = f2bf(W1[k * 256 + n]);
  } else if (tid < 98304) {
    int t2 = tid - 32768;
    int j = t2 & 7, l = (t2 >> 3) & 63, frag = t2 >> 9;      // frag 0..127
    int nt = frag >> 4, kt = frag & 15;
    int n = nt * 32 + (l & 31);
    int k = kt * 16 + ((l >> 5) * 8) + j;
    pW2[t2] = f2bf(W2[k * 256 + n]);
  } else {
    int c = tid - 98304;
    int tu = Nu * 8;
    int total = tu + Nm * 8;
    if (c < total) {
      const float* s; short* d;
      if (c < tu) { s = xu + (size_t)c * 8; d = xub + (size_t)c * 8; }
      else { int c2 = c - tu; s = xm + (size_t)c2 * 8; d = xmb + (size_t)c2 * 8; }
      v4f a = *(const v4f*)s, b = *(const v4f*)(s + 4);
      v4u o = { pk2(a[0], a[1]), pk2(a[2], a[3]), pk2(b[0], b[1]), pk2(b[2], b[3]) };
      *(v4u*)d = o;
    }
  }
}

#define LDX_S 136   // 128 + 8 pad shorts
#define LDH_S 264   // 256 + 8 pad shorts
#define LDP13 12    // 8 slots + 4 pad floats
#define XBUF (64 * LDX_S)    // 8704 shorts / buffer
#define HBUF (64 * LDH_S)    // 16896 shorts / buffer
#define PBUF13 (64 * LDP13)  // 768 floats / buffer
#define SMEM13 (2*XBUF*2 + 2*HBUF*2 + 2*PBUF13*4)   // 108544 B

// v13 = v12 structure with 32x32x16 MFMA (m119: 2495 TF vs 2075 for 16x16 ->
// ~17% fewer MFMA-pipe cycles, half the MFMA instructions). Same roles:
// 4 A-waves (gather bf16 + commit X + L1 + P-store on wg0), 4 B-waves
// (L2 + bias/ReLU + W3 fold), 1A+1B per SIMD; single-barrier 3-deep pipeline.
// Occupancy is register-bound at 2 waves/SIMD (B: rW2 128 + acc 32 + misc),
// so tiles/LDS kept identical to v12. 32x32 C/D layout (m74-verified):
//   col = lane&31, row = (reg&3) + 8*(reg>>2) + 4*(lane>>5).
// B-operand: lane l holds B[k = kt*16 + (l>>5)*8 + j][col = l&31].
__global__ __launch_bounds__(512, 2) void mlp_v13(
    const short* __restrict__ xub, const short* __restrict__ xmb,
    const void* __restrict__ eidx,
    const short* __restrict__ pW1, const short* __restrict__ pW2,
    const float* __restrict__ b1, const float* __restrict__ b2,
    const float* __restrict__ W3, const float* __restrict__ b3,
    float* __restrict__ out, int E)
{
  extern __shared__ __align__(16) char smem[];
  short* ldsX = (short*)smem;                       // [2][XBUF]
  short* ldsH = (short*)(smem + 2 * XBUF * 2);      // [2][HBUF]
  float* ldsP = (float*)(smem + 2 * XBUF * 2 + 2 * HBUF * 2); // [2][PBUF13]

  const int t    = threadIdx.x;
  const int w    = t >> 6;
  const int lane = t & 63;
  const int lp5  = lane & 31;
  const int hi   = lane >> 5;
  const int wg   = w >> 1;
  const bool isA = (((w & 1) ^ ((w >> 2) & 1)) == 0);

  const unsigned* ew = (const unsigned*)eidx;
  unsigned oddw = (lane < 32) ? ew[2 * lane + 1] : 0u;
  const bool i64 = (__ballot(oddw != 0u) == 0ull);

  const int ntiles = (E + 63) >> 6;
  const int S   = (int)gridDim.x;
  const int bid = (int)blockIdx.x;
  const int Tb  = (ntiles - bid + S - 1) / S;
  const float bias3 = b3[0];

  if (isA) {
    // ===== producer: gather (bf16) + layer 1 (+ store on wg==0) =====
    const v8s* w1v = (const v8s*)pW1;
    v8s rW1[2][8];                      // 64 VGPR: out rows wg*64 + rowt*32 + (l&31)
#pragma unroll
    for (int rowt = 0; rowt < 2; ++rowt)
#pragma unroll
      for (int kt = 0; kt < 8; ++kt)
        rW1[rowt][kt] = w1v[(((wg * 2 + rowt) * 8) + kt) * 64 + lane];
    v4f rb1[2][4];                      // bias rows wg*64 + rowt*32 + g*8 + hi*4 ..+3
#pragma unroll
    for (int rowt = 0; rowt < 2; ++rowt)
#pragma unroll
      for (int g = 0; g < 4; ++g)
        rb1[rowt][g] = *(const v4f*)(b1 + wg * 64 + rowt * 32 + g * 8 + hi * 4);

    const int ra = wg * 64 + lane;      // 4 threads/edge
    const int gi = ra >> 2, gq = ra & 3;

    auto loadIdx = [&](int tl, int& row, int& col) {
      int gE = tl * 64 + gi;
      if (gE >= E || gE < 0) gE = 0;
      if (i64) {
        const long long* p = (const long long*)eidx;
        row = (int)p[gE]; col = (int)p[(long long)E + gE];
      } else {
        const int* p = (const int*)eidx;
        row = p[gE]; col = p[E + gE];
      }
    };

    v4u u0, u1, m0, m1;
    auto issueUM = [&](int row, int col) {
      const v4u* pu = (const v4u*)(xub + (size_t)row * 64 + gq * 16);
      const v4u* pm = (const v4u*)(xmb + (size_t)col * 64 + gq * 16);
      u0 = pu[0]; u1 = pu[1]; m0 = pm[0]; m1 = pm[1];
    };

    int rowN, colN;
    loadIdx(bid, rowN, colN);
    issueUM(rowN, colN);
    loadIdx(bid + S, rowN, colN);

    for (int k = 0; k <= Tb + 2; ++k) {
      __syncthreads();
      const int pb = k & 1;
      const int tg = bid + k * S;

      // ---- commit prefetched bf16 features -> ldsX[pb]
      if (k < Tb) {
        short* px = &ldsX[pb * XBUF + gi * LDX_S + gq * 16];
        *(v4u*)(px)      = u0;  *(v4u*)(px + 8)  = u1;   // user  -> k 0..63
        *(v4u*)(px + 64) = m0;  *(v4u*)(px + 72) = m1;   // movie -> k 64..127
      }
      // ---- prefetch features(t_{k+1}), indices(t_{k+2})
      if (k + 1 < Tb) {
        issueUM(rowN, colN);
        loadIdx(tg + 2 * S, rowN, colN);
      }

      // ---- reduce + store tile t3 from ldsP[pb^1] (wave wg==0, lane = edge)
      const int t3 = tg - 3 * S;
      if (t3 >= 0 && wg == 0) {
        const v4f* pp = (const v4f*)&ldsP[(pb ^ 1) * PBUF13 + lane * LDP13];
        v4f p0 = pp[0], p1 = pp[1];
        float r = bias3 + (p0[0] + p0[1]) + (p0[2] + p0[3])
                        + (p1[0] + p1[1]) + (p1[2] + p1[3]);
        int o = t3 * 64 + lane;
        if (o < E) out[o] = r;
      }

      // ---- layer 1 of t1 : ldsX[pb^1] -> ldsH[pb^1]
      const int t1 = tg - S;
      if (t1 >= 0 && t1 < ntiles) {
        const short* xb = &ldsX[(pb ^ 1) * XBUF];
        short* hb = &ldsH[(pb ^ 1) * HBUF];
#pragma unroll 1
        for (int colt = 0; colt < 2; ++colt) {      // 32-edge column tiles
          v16f a0, a1;                              // acc live = 32 VGPR
#pragma unroll
          for (int g = 0; g < 4; ++g)
#pragma unroll
            for (int rr = 0; rr < 4; ++rr) {
              a0[4 * g + rr] = rb1[0][g][rr];
              a1[4 * g + rr] = rb1[1][g][rr];
            }
          __builtin_amdgcn_s_setprio(1);
#pragma unroll
          for (int kt = 0; kt < 8; ++kt) {
            v8s bf = *(const v8s*)&xb[(colt * 32 + lp5) * LDX_S + kt * 16 + hi * 8];
            a0 = __builtin_amdgcn_mfma_f32_32x32x16_bf16(rW1[0][kt], bf, a0, 0, 0, 0);
            a1 = __builtin_amdgcn_mfma_f32_32x32x16_bf16(rW1[1][kt], bf, a1, 0, 0, 0);
          }
          __builtin_amdgcn_s_setprio(0);
          // relu + pack + H write: rows wg*64 + rowt*32 + g*8 + hi*4 ..+3
          const int e = colt * 32 + lp5;
#pragma unroll
          for (int g = 0; g < 4; ++g) {
            v2u pw;
            pw.x = pk2(fmaxf(a0[4 * g + 0], 0.f), fmaxf(a0[4 * g + 1], 0.f));
            pw.y = pk2(fmaxf(a0[4 * g + 2], 0.f), fmaxf(a0[4 * g + 3], 0.f));
            *(v2u*)&hb[e * LDH_S + wg * 64 + g * 8 + hi * 4] = pw;
            v2u qw;
            qw.x = pk2(fmaxf(a1[4 * g + 0], 0.f), fmaxf(a1[4 * g + 1], 0.f));
            qw.y = pk2(fmaxf(a1[4 * g + 2], 0.f), fmaxf(a1[4 * g + 3], 0.f));
            *(v2u*)&hb[e * LDH_S + wg * 64 + 32 + g * 8 + hi * 4] = qw;
          }
        }
      }
    }
  } else {
    // ===== consumer: layer 2 + bias/ReLU + W3 fold =====
    const v8s* w2v = (const v8s*)pW2;
    v8s rW2[2][16];                     // 128 VGPR: out rows wg*64 + rowt*32 + (l&31)
#pragma unroll
    for (int rowt = 0; rowt < 2; ++rowt)
#pragma unroll
      for (int kt = 0; kt < 16; ++kt)
        rW2[rowt][kt] = w2v[(((wg * 2 + rowt) * 16) + kt) * 64 + lane];
    // b2 packed bf16 (16 regs; exact when b2==0, <=bf16-ulp otherwise), W3 f32
    v2u rb2p[2][4]; v4f rw3[2][4];
#pragma unroll
    for (int rowt = 0; rowt < 2; ++rowt)
#pragma unroll
      for (int g = 0; g < 4; ++g) {
        int o = wg * 64 + rowt * 32 + g * 8 + hi * 4;
        v4f bb = *(const v4f*)(b2 + o);
        rb2p[rowt][g].x = pk2(bb[0], bb[1]);
        rb2p[rowt][g].y = pk2(bb[2], bb[3]);
        rw3[rowt][g] = *(const v4f*)(W3 + o);
      }

    for (int k = 0; k <= Tb + 2; ++k) {
      __syncthreads();
      const int pb = k & 1;
      const int tg = bid + k * S;
      const int t2 = tg - 2 * S;
      if (t2 >= 0 && t2 < ntiles) {
        const short* hbr = &ldsH[pb * HBUF];
        float* pPw = &ldsP[pb * PBUF13];
#pragma unroll 1
        for (int colt = 0; colt < 2; ++colt) {
          v16f a0, a1;                              // acc live = 32 VGPR
#pragma unroll
          for (int g = 0; g < 4; ++g) {
            a0[4 * g + 0] = bflo(rb2p[0][g].x); a0[4 * g + 1] = bfhi(rb2p[0][g].x);
            a0[4 * g + 2] = bflo(rb2p[0][g].y); a0[4 * g + 3] = bfhi(rb2p[0][g].y);
            a1[4 * g + 0] = bflo(rb2p[1][g].x); a1[4 * g + 1] = bfhi(rb2p[1][g].x);
            a1[4 * g + 2] = bflo(rb2p[1][g].y); a1[4 * g + 3] = bfhi(rb2p[1][g].y);
          }
          __builtin_amdgcn_s_setprio(1);
#pragma unroll
          for (int kt = 0; kt < 16; ++kt) {
            v8s bf = *(const v8s*)&hbr[(colt * 32 + lp5) * LDH_S + kt * 16 + hi * 8];
            a0 = __builtin_amdgcn_mfma_f32_32x32x16_bf16(rW2[0][kt], bf, a0, 0, 0, 0);
            a1 = __builtin_amdgcn_mfma_f32_32x32x16_bf16(rW2[1][kt], bf, a1, 0, 0, 0);
          }
          __builtin_amdgcn_s_setprio(0);
          float s = 0.f;
#pragma unroll
          for (int g = 0; g < 4; ++g)
#pragma unroll
            for (int rr = 0; rr < 4; ++rr) {
              s += fmaxf(a0[4 * g + rr], 0.f) * rw3[0][g][rr];
              s += fmaxf(a1[4 * g + rr], 0.f) * rw3[1][g][rr];
            }
          // partial sum slot: 4 wg x 2 hi = 8 slots per edge
          pPw[(colt * 32 + lp5) * LDP13 + wg * 2 + hi] = s;
        }
      }
    }
  }
}

extern "C" void kernel_launch(void* const* d_in, const int* in_sizes, int n_in,
                              void* d_out, int out_size, void* d_ws, size_t ws_size,
                              hipStream_t stream) {
  const float* xu  = (const float*)d_in[0];
  const float* xm  = (const float*)d_in[1];
  const void*  ei  = d_in[2];
  const float* W1  = (const float*)d_in[3];
  const float* b1  = (const float*)d_in[4];
  const float* W2  = (const float*)d_in[5];
  const float* b2  = (const float*)d_in[6];
  const float* W3  = (const float*)d_in[7];
  const float* b3  = (const float*)d_in[8];
  float* out = (float*)d_out;

  const int E  = in_sizes[2] / 2;
  const int Nu = in_sizes[0] / 64;
  const int Nm = in_sizes[1] / 64;

  short* pW1 = (short*)d_ws;          // 64 KB
  short* pW2 = pW1 + 32768;           // 128 KB
  short* xub = (short*)((char*)d_ws + 196608);
  short* xmb = xub + (size_t)Nu * 64;

  const int cvt_blocks = ((Nu + Nm) * 8 + 255) / 256;
  hipLaunchKernelGGL(prep, dim3(384 + cvt_blocks), dim3(256), 0, stream,
                     W1, W2, xu, xm, pW1, pW2, xub, xmb, Nu, Nm);

  hipFuncSetAttribute((const void*)mlp_v13,
                      hipFuncAttributeMaxDynamicSharedMemorySize, SMEM13);

  const int ntiles = (E + 63) / 64;
  const int nblk = ntiles < 256 ? ntiles : 256;
  hipLaunchKernelGGL(mlp_v13, dim3(nblk), dim3(512), SMEM13, stream,
                     xub, xmb, ei, pW1, pW2, b1, b2, W3, b3, out, E);
}